// Round 7
// baseline (436.788 us; speedup 1.0000x reference)
//
#include <hip/hip_runtime.h>

// MMCL hard-negative CE loss, single-label path.
// B=2048 rows, N=32768 logits/row, k=int(0.01*(N-1))=327.
//
// Persistent kernel: grid=256 (1 block/CU), each block handles 8 consecutive
// rows. Per row: stage full row in LDS as monotone uint32 keys, fused with a
// 12-bit MSB histogram + row-max + positive capture during the single HBM
// read; suffix-scan -> boundary digit d0; compact keys >= d0<<20 (~540) into
// a small buffer; pairwise-rank -> exact threshold key T + tie count r;
// exp-sum over selected + positive. Per-block partial -> d_ws, then a
// deterministic fixed-order reduce kernel writes out[0].
//
// Next row's 32 elements/thread are prefetched into registers inside the
// current row's phase A. All in-loop barriers are RAW s_barrier preceded by
// s_waitcnt lgkmcnt(0) ONLY (HK pattern, T4): __syncthreads() would emit
// vmcnt(0) and drain the prefetch, serializing load-wait with the selection
// tail. With lgkm-only barriers the tail runs while next row's loads fly.
//
// R4: de-aliased scratch (row max/pos at miscf[40]/[41], clear of phase-B
// totals at misc[24..39]). R5: wave-aggregated phase-C compaction (4 ballots
// + 1 atomic per wave-iter). R6: block-local loss accumulator. R7: replace
// the fp32 output atomic with a two-stage deterministic reduction (partials
// in d_ws, fixed-order reduce kernel) — bitwise-stable across graph replays.

#define NTHREADS 1024
#define NQ       8       // float4 loads per thread: N/4/NTHREADS (N=32768)
#define CAP      2048    // candidate buffer capacity (expected M ~ 540)
#define GRIDMAX  256

__device__ __forceinline__ void bar_lds() {
    // order LDS ops across the barrier; do NOT drain vmcnt (prefetch in flight)
    asm volatile("s_waitcnt lgkmcnt(0)" ::: "memory");
    __builtin_amdgcn_s_barrier();
}

__device__ __forceinline__ unsigned f2key(float x) {
    unsigned u = __float_as_uint(x);
    return (u & 0x80000000u) ? ~u : (u | 0x80000000u);  // monotone: bigger float -> bigger key
}
__device__ __forceinline__ float key2f(unsigned k) {
    unsigned u = (k & 0x80000000u) ? (k & 0x7FFFFFFFu) : ~k;
    return __uint_as_float(u);
}

__global__ __launch_bounds__(NTHREADS)
void mmcl_loss_kernel(const float* __restrict__ logits,
                      const int*   __restrict__ targets,
                      float*       __restrict__ ws,
                      int N, int B, int K, float invB, int rpb)
{
    extern __shared__ unsigned smem[];
    unsigned* keys = smem;                  // N keys (128 KiB)
    unsigned* hist = smem + N;              // 4096 bins
    unsigned* cand = hist + 4096;           // CAP + 4 pad
    unsigned* misc = cand + CAP + 4;        // 64 scalars
    float*    miscf = (float*)misc;
    // misc[0]=d0  misc[1]=cand count  misc[2]=T key  misc[3]=tie count r
    // miscf[8..23]=per-wave float partials (max in A, expsum in E)
    // misc[24..39]=phase-B per-wave suffix totals (private to phase B)
    // miscf[40]=row max  miscf[41]=positive logit

    const int tid  = threadIdx.x;
    const int lane = tid & 63;
    const int wid  = tid >> 6;
    const unsigned Ku = (unsigned)K;
    const int nvec = N >> 2;

    const int rowBeg = blockIdx.x * rpb;
    const int rowEnd = min(rowBeg + rpb, B);
    if (rowBeg >= rowEnd) {                 // degenerate split: still publish 0
        if (tid == 0) ws[blockIdx.x] = 0.f;
        return;
    }

    // prologue: issue first row's loads ASAP, then init LDS under them
    float4 R[NQ];
    {
        const float4* rp = (const float4*)(logits + (size_t)rowBeg * (size_t)N);
        #pragma unroll
        for (int q = 0; q < NQ; ++q) R[q] = rp[tid + (q << 10)];
    }
    for (int i = tid; i < 4096; i += NTHREADS) hist[i] = 0u;
    if (tid < 64) misc[tid] = 0u;
    float blockLoss = 0.f;                 // tid==0 accumulator across rows
    __syncthreads();   // full drain OK here: phase A needs row 0 data anyway

    for (int row = rowBeg; row < rowEnd; ++row) {
        const int tgt = targets[row];
        const bool haveNext = (row + 1 < rowEnd);                      // block-uniform
        const float4* nxt = (const float4*)(logits + (size_t)(haveNext ? row + 1 : row) * (size_t)N);

        // ---- phase A: regs -> LDS keys + 12-bit MSB histogram + max + pos;
        //      prefetch next row into the just-freed registers ----
        float lmax = -3.4e38f;
        #pragma unroll
        for (int q = 0; q < NQ; ++q) {
            float4 v = R[q];
            if (haveNext) R[q] = nxt[tid + (q << 10)];   // issue next-row load early
            const int i4 = tid + (q << 10);
            const int c  = i4 << 2;
            unsigned k0 = f2key(v.x), k1 = f2key(v.y), k2 = f2key(v.z), k3 = f2key(v.w);
            lmax = fmaxf(lmax, fmaxf(fmaxf(v.x, v.y), fmaxf(v.z, v.w)));
            if (c + 0 == tgt) { miscf[41] = v.x; k0 = 0u; }   // mask positive out of negatives
            if (c + 1 == tgt) { miscf[41] = v.y; k1 = 0u; }
            if (c + 2 == tgt) { miscf[41] = v.z; k2 = 0u; }
            if (c + 3 == tgt) { miscf[41] = v.w; k3 = 0u; }
            uint4 kk; kk.x = k0; kk.y = k1; kk.z = k2; kk.w = k3;
            ((uint4*)keys)[i4] = kk;
            atomicAdd(&hist[k0 >> 20], 1u);
            atomicAdd(&hist[k1 >> 20], 1u);
            atomicAdd(&hist[k2 >> 20], 1u);
            atomicAdd(&hist[k3 >> 20], 1u);
        }
        // block max reduce
        for (int d = 32; d > 0; d >>= 1) lmax = fmaxf(lmax, __shfl_down(lmax, d));
        if (lane == 0) miscf[8 + wid] = lmax;
        bar_lds();                                   // A-end: keys/hist/partials visible
        if (tid == 0) {
            float m = miscf[8];
            for (int w = 1; w < 16; ++w) m = fmaxf(m, miscf[8 + w]);
            miscf[40] = m;                           // read at D-end
        }

        // ---- phase B: digit d0 (bins of key>>20) containing the K-th largest ----
        {
            unsigned c0 = hist[4*tid+0], c1 = hist[4*tid+1], c2 = hist[4*tid+2], c3 = hist[4*tid+3];
            unsigned ps = c0 + c1 + c2 + c3;
            unsigned s  = ps;                      // wave suffix: sum over lanes >= lane
            for (int d = 1; d < 64; d <<= 1) {
                unsigned t = __shfl_down(s, d);
                if (lane + d < 64) s += t;
            }
            if (lane == 0) misc[24 + wid] = s;     // per-wave totals (private slots)
            bar_lds();                             // B-internal
            unsigned wab = 0;
            for (int w = wid + 1; w < 16; ++w) wab += misc[24 + w];
            unsigned above = (s - ps) + wab;       // count in bins > 4*tid+3
            unsigned a3 = above, a2 = a3 + c3, a1 = a2 + c2, a0 = a1 + c1;
            if (a3 < Ku && Ku <= a3 + c3) misc[0] = (unsigned)(4*tid + 3);
            if (a2 < Ku && Ku <= a2 + c2) misc[0] = (unsigned)(4*tid + 2);
            if (a1 < Ku && Ku <= a1 + c1) misc[0] = (unsigned)(4*tid + 1);
            if (a0 < Ku && Ku <= a0 + c0) misc[0] = (unsigned)(4*tid + 0);
        }
        bar_lds();                                 // B-end: d0 visible
        const unsigned d0   = misc[0];
        const unsigned thr0 = d0 << 20;

        // hist is dead (all reads pre-B-internal) -> zero for next row,
        // overlapped with compaction
        { uint4 z; z.x = z.y = z.z = z.w = 0u; ((uint4*)hist)[tid] = z; }

        // ---- phase C: wave-aggregated compaction of keys >= thr0 ----
        for (int i4 = tid; i4 < nvec; i4 += NTHREADS) {
            uint4 kk = ((uint4*)keys)[i4];
            const bool p0 = kk.x >= thr0, p1 = kk.y >= thr0,
                       p2 = kk.z >= thr0, p3 = kk.w >= thr0;
            unsigned long long b0 = __ballot(p0), b1 = __ballot(p1),
                               b2 = __ballot(p2), b3 = __ballot(p3);
            const unsigned t0 = (unsigned)__popcll(b0), t1 = (unsigned)__popcll(b1),
                           t2 = (unsigned)__popcll(b2), t3 = (unsigned)__popcll(b3);
            const unsigned tot = t0 + t1 + t2 + t3;
            if (tot) {                              // wave-uniform
                unsigned base = 0;
                if (lane == 0) base = atomicAdd(&misc[1], tot);
                base = __shfl(base, 0);
                const unsigned long long lm = (1ull << lane) - 1ull;
                const unsigned o0 = base + (unsigned)__popcll(b0 & lm);
                const unsigned o1 = base + t0 + (unsigned)__popcll(b1 & lm);
                const unsigned o2 = base + t0 + t1 + (unsigned)__popcll(b2 & lm);
                const unsigned o3 = base + t0 + t1 + t2 + (unsigned)__popcll(b3 & lm);
                if (p0 && o0 < CAP) cand[o0] = kk.x;
                if (p1 && o1 < CAP) cand[o1] = kk.y;
                if (p2 && o2 < CAP) cand[o2] = kk.z;
                if (p3 && o3 < CAP) cand[o3] = kk.w;
            }
        }
        bar_lds();                                 // C-end: M + cand visible
        const unsigned M = misc[1];
        const bool fellback = (M > CAP);           // block-uniform

        if (!fellback && tid < 4) cand[M + tid] = 0u;   // pad to uint4 multiple (sentinel 0)
        bar_lds();                                 // pad visible

        // ---- phase D: exact threshold via pairwise rank (broadcast LDS reads) ----
        if (!fellback) {
            int m4 = (int)((M + 3) >> 2);
            for (int t = tid; t < (int)M; t += NTHREADS) {
                unsigned km = cand[t];
                unsigned cgt = 0, ceq = 0;
                for (int i = 0; i < m4; ++i) {
                    uint4 q = ((uint4*)cand)[i];
                    cgt += (q.x > km); ceq += (q.x == km);
                    cgt += (q.y > km); ceq += (q.y == km);
                    cgt += (q.z > km); ceq += (q.z == km);
                    cgt += (q.w > km); ceq += (q.w == km);
                }
                // all writers (tied copies of the K-th value) carry identical data
                if (cgt < Ku && Ku <= cgt + ceq) { misc[2] = km; misc[3] = Ku - cgt; }
            }
        } else {
            // correctness fallback (never triggers on N(0,1) data): rank boundary-
            // digit keys against the full key array. Slow but exact.
            for (int t = tid; t < N; t += NTHREADS) {
                unsigned km = keys[t];
                if ((km >> 20) != d0) continue;
                unsigned cgt = 0, ceq = 0;
                for (int i = 0; i < nvec; ++i) {
                    uint4 q = ((uint4*)keys)[i];
                    cgt += (q.x > km); ceq += (q.x == km);
                    cgt += (q.y > km); ceq += (q.y == km);
                    cgt += (q.z > km); ceq += (q.z == km);
                    cgt += (q.w > km); ceq += (q.w == km);
                }
                if (cgt < Ku && Ku <= cgt + ceq) { misc[2] = km; misc[3] = Ku - cgt; }
            }
        }
        bar_lds();                                 // D-end: T, r, maxv visible
        const unsigned T = misc[2];
        const unsigned r = misc[3];
        const float maxv = miscf[40];

        // ---- phase E: exp-sum over selected negatives (> T; ties via r) ----
        float s = 0.f;
        if (!fellback) {
            for (int t = tid; t < (int)M; t += NTHREADS) {
                unsigned kk = cand[t];
                if (kk > T) s += expf(10.f * (key2f(kk) - maxv));
            }
        } else {
            for (int i4 = tid; i4 < nvec; i4 += NTHREADS) {
                uint4 q = ((uint4*)keys)[i4];
                if (q.x > T) s += expf(10.f * (key2f(q.x) - maxv));
                if (q.y > T) s += expf(10.f * (key2f(q.y) - maxv));
                if (q.z > T) s += expf(10.f * (key2f(q.z) - maxv));
                if (q.w > T) s += expf(10.f * (key2f(q.w) - maxv));
            }
        }
        for (int d = 32; d > 0; d >>= 1) s += __shfl_down(s, d);
        if (lane == 0) miscf[8 + wid] = s;
        bar_lds();                                 // E-internal: partials visible
        if (tid == 0) {
            float tot = 0.f;
            for (int w = 0; w < 16; ++w) tot += miscf[8 + w];
            float posv = miscf[41];
            tot += (float)r * expf(10.f * (key2f(T) - maxv));   // tie copies at threshold
            tot += expf(10.f * (posv - maxv));                  // positive term
            blockLoss += 10.f * maxv + logf(tot) - 10.f * posv;
        }
        if (tid == 1) misc[1] = 0u;                // reset compact counter
        bar_lds();                                 // row-end: protect keys/hist/misc
    }

    if (tid == 0) ws[blockIdx.x] = blockLoss * invB;   // plain store, no atomic
}

// Deterministic fixed-order reduction of per-block partials -> out[0].
__global__ __launch_bounds__(256)
void reduce_partials_kernel(const float* __restrict__ ws, float* __restrict__ out, int n)
{
    __shared__ float wsum[4];
    const int tid  = threadIdx.x;
    const int lane = tid & 63;
    const int wid  = tid >> 6;
    float s = 0.f;
    for (int i = tid; i < n; i += 256) s += ws[i];       // fixed mapping
    for (int d = 32; d > 0; d >>= 1) s += __shfl_down(s, d);
    if (lane == 0) wsum[wid] = s;
    __syncthreads();
    if (tid == 0) out[0] = (wsum[0] + wsum[1]) + (wsum[2] + wsum[3]);
}

extern "C" void kernel_launch(void* const* d_in, const int* in_sizes, int n_in,
                              void* d_out, int out_size, void* d_ws, size_t ws_size,
                              hipStream_t stream)
{
    const float* logits  = (const float*)d_in[0];
    const int*   targets = (const int*)d_in[1];
    float*       out     = (float*)d_out;
    float*       ws      = (float*)d_ws;

    const int B = in_sizes[1];
    const int N = in_sizes[0] / B;                 // 32768
    const int K = (int)(0.01 * (double)(N - 1));   // 327

    const int nblk = (B < GRIDMAX) ? B : GRIDMAX;  // persistent: 1 block/CU
    const int rpb  = (B + nblk - 1) / nblk;        // rows per block (8)

    const size_t shmem = (size_t)(N + 4096 + CAP + 4 + 64) * sizeof(unsigned); // ~152 KiB
    hipFuncSetAttribute((const void*)mmcl_loss_kernel,
                        hipFuncAttributeMaxDynamicSharedMemorySize, (int)shmem);

    mmcl_loss_kernel<<<nblk, NTHREADS, shmem, stream>>>(logits, targets, ws,
                                                        N, B, K, 1.0f / (float)B, rpb);
    reduce_partials_kernel<<<1, 256, 0, stream>>>(ws, out, nblk);
}